// Round 11
// baseline (161.511 us; speedup 1.0000x reference)
//
#include <hip/hip_runtime.h>
#include <hip/hip_bf16.h>
#include <stdint.h>
#include <stddef.h>

#define NB 32
#define NN 8192
#define NH 512
#define NE 10
#define HEPS 1e-5f
#define HSLOPE 0.2f

typedef short short8 __attribute__((ext_vector_type(8)));
typedef float f32x4 __attribute__((ext_vector_type(4)));
typedef float f32x16 __attribute__((ext_vector_type(16)));

static __device__ __forceinline__ unsigned short sbf(float a){
  __hip_bfloat16 t = __float2bfloat16(a);
  return *reinterpret_cast<unsigned short*>(&t);
}
static __device__ __forceinline__ unsigned pkbf(float a, float b){
  float2 f2; f2.x = a; f2.y = b;
  __hip_bfloat162 t = __float22bfloat162_rn(f2);
  return *reinterpret_cast<unsigned*>(&t);
}

// ---------------------------------------------------------------------------
// Prep: W2 [E][512][256] f32 -> bf16 image for 32x32x16 fragments (as R10).
// [e][t(32)][col(256)][kh(2)][kk(8)]: a wave's 32-col frag at k-step t is
// one coalesced 16B/lane load.
// ---------------------------------------------------------------------------
__global__ __launch_bounds__(256) void prep_w2(const float* __restrict__ W2,
                                               unsigned short* __restrict__ ws){
  int idx = blockIdx.x * 256 + threadIdx.x;
  int col = idx & 255;
  int k   = (idx >> 8) & 511;
  int e   = idx >> 17;
  int t = k >> 4, kh = (k >> 3) & 1, kk = k & 7;
  ws[(((size_t)(e * 32 + t)) << 12) + (col << 4) + (kh << 3) + kk] = sbf(W2[idx]);
}

// ---------------------------------------------------------------------------
// Main (R11): R10 pipeline at 8 waves/block (512 thr), BM=32, 32KB LDS ->
// 4 blocks/CU x 8 waves = 32 waves/CU (full occupancy; was 16). Wave owns
// 32 W2-cols (1 m-frag); per-thread state halves -> fits 64-VGPR cap that
// 8 waves/SIMD requires (launch_bounds(512,4): empirically 64-VGPR cap).
//  L1  : 2 MFMA (64 feature-cols/wave), LN1 local+1shfl+stf[32][8][2];
//        normalize+lrelu -> packed uint2 frag-major As (conflict-free).
//  GEMM: 32 k-steps x {1 ds_read_b128, 1x16B B-load, 1 MFMA}, 3-deep B.
//  EPI : +b2, LN2 local+1shfl+stf, lrelu, layer3 f32x4, opart[32][8][3].
// ---------------------------------------------------------------------------
template<bool PREP>
__global__ __launch_bounds__(512, 4) void mlp_main(
  const float* __restrict__ points, const int* __restrict__ cats,
  const float* __restrict__ W1, const float* __restrict__ b1,
  const float* __restrict__ g1, const float* __restrict__ be1,
  const float* __restrict__ W2f, const float* __restrict__ b2,
  const float* __restrict__ g2, const float* __restrict__ be2,
  const float* __restrict__ W3, const float* __restrict__ b3,
  const unsigned short* __restrict__ W2s,
  float* __restrict__ out)
{
  __shared__ unsigned short As[32 * 512];   // 32KB; frag t at [t*512]: [kh(2)][pr(32)][kk(8)]
  float* stf = (float*)As;                  // stats alias floats [0..512); opart [512..1280)

  const int tid  = (int)threadIdx.x;
  const int lane = tid & 63;
  const int w    = tid >> 6;            // wave 0..7
  const int pr   = lane & 31;           // point-row (C col)
  const int kh   = lane >> 5;           // k-half
  const size_t row0 = (size_t)blockIdx.x * 32;
  const int e = cats[row0 >> 13];
  const int wbase = w * 32;             // GEMM: wave's 32 W2-cols

  // ---------------- layer1 via 32x32x16 MFMA (64 feature-cols/wave) --------
  f32x16 a1[2];
  float al1, bt1;
  {
    const float* W1e = W1 + (size_t)e * 3 * NH;
    const float* b1e = b1 + (size_t)e * NH;
    short8 apf;                         // points as B-operand (n = point-row)
    {
      const float* pp = points + (row0 + pr) * 3;
      union { short8 s; unsigned u[4]; } v;
      v.s = short8{0,0,0,0,0,0,0,0};
      if(kh == 0){ v.u[0] = pkbf(pp[0], pp[1]); v.u[1] = pkbf(pp[2], 1.0f); }
      apf = v.s;
    }
    #pragma unroll
    for(int mi = 0; mi < 2; mi++){
      int col = w * 64 + mi * 32 + pr;       // A-operand m = lane&31
      union { short8 s; unsigned u[4]; } bw;
      bw.s = short8{0,0,0,0,0,0,0,0};
      if(kh == 0){
        bw.u[0] = pkbf(W1e[col], W1e[NH + col]);
        bw.u[1] = pkbf(W1e[2 * NH + col], b1e[col]);
      }
      f32x16 z = {0.f,0.f,0.f,0.f,0.f,0.f,0.f,0.f,0.f,0.f,0.f,0.f,0.f,0.f,0.f,0.f};
      a1[mi] = __builtin_amdgcn_mfma_f32_32x32x16_bf16(bw.s, apf, z, 0, 0, 0);
    }
    // LN1 stats: all lane values belong to point-row pr
    float s = 0.f, q = 0.f;
    #pragma unroll
    for(int mi = 0; mi < 2; mi++)
      #pragma unroll
      for(int r = 0; r < 16; r++){ float x = a1[mi][r]; s += x; q = fmaf(x, x, q); }
    s += __shfl_xor(s, 32); q += __shfl_xor(q, 32);
    if(kh == 0){
      float2 sq; sq.x = s; sq.y = q;
      *(float2*)(&stf[pr * 16 + w * 2]) = sq;
    }
    __syncthreads();
    {
      float ssum = 0.f, qsum = 0.f;
      #pragma unroll
      for(int u = 0; u < 4; u++){
        f32x4 v = *(const f32x4*)&stf[pr * 16 + u * 4];
        ssum += v[0] + v[2]; qsum += v[1] + v[3];
      }
      float mu = ssum * (1.f / NH);
      float rs = rsqrtf(fmaf(-mu, mu, qsum * (1.f / NH)) + HEPS);
      al1 = rs; bt1 = -mu * rs;
    }
    __syncthreads();   // stf fully read before As overwrite
  }
  // normalize + lrelu -> packed uint2 into frag-major As
  {
    const float* g1e  = g1  + (size_t)e * NH;
    const float* be1e = be1 + (size_t)e * NH;
    #pragma unroll
    for(int mi = 0; mi < 2; mi++){
      #pragma unroll
      for(int g = 0; g < 4; g++){
        int cb = w * 64 + mi * 32 + g * 8 + kh * 4;   // 4 feature cols
        f32x4 gg = *(const f32x4*)(g1e + cb);
        f32x4 ee = *(const f32x4*)(be1e + cb);
        float xr[4];
        #pragma unroll
        for(int j = 0; j < 4; j++){
          float x = fmaf(a1[mi][g * 4 + j], al1, bt1);
          x = fmaf(x, gg[j], ee[j]);
          xr[j] = fmaxf(x, HSLOPE * x);
        }
        uint2 pk; pk.x = pkbf(xr[0], xr[1]); pk.y = pkbf(xr[2], xr[3]);
        int t = w * 4 + mi * 2 + (g >> 1);
        int addr = (t << 9) + ((g & 1) << 8) + pr * 8 + kh * 4;
        *(uint2*)(&As[addr]) = pk;
      }
    }
  }

  // ---------------- B prefetch (W2 as A-operand, 1 frag/step) ----------------
  auto loadB = [&](short8* dst, int t){
    if constexpr (PREP){
      const unsigned short* p = W2s + (((size_t)(e * 32 + t)) << 12)
                              + ((wbase + pr) << 4) + (kh << 3);
      *dst = *(const short8*)p;
    } else {
      const float* p = W2f + (((size_t)e * 512 + t * 16 + kh * 8) << 8)
                     + (wbase + pr);
      short8 v;
      #pragma unroll
      for(int kk = 0; kk < 8; kk++) v[kk] = (short)sbf(p[(size_t)kk << 8]);
      *dst = v;
    }
  };
  short8 bfr[3];
  loadB(&bfr[0], 0); loadB(&bfr[1], 1); loadB(&bfr[2], 2);

  __syncthreads();   // As complete

  // ---------------- GEMM: 32 barrier-free k-steps ----------------
  f32x16 acc;
  {
    f32x16 z = {0.f,0.f,0.f,0.f,0.f,0.f,0.f,0.f,0.f,0.f,0.f,0.f,0.f,0.f,0.f,0.f};
    acc = z;
  }
  const int aoff = (kh << 8) + pr * 8;
  short8 afA, afB;
  afA = *(const short8*)&As[aoff];

  #pragma unroll
  for(int t = 0; t < 32; t++){
    short8 af = (t & 1) ? afB : afA;
    if(t < 31){
      short8 nx = *(const short8*)&As[((t + 1) << 9) + aoff];
      if(t & 1) afA = nx; else afB = nx;
    }
    acc = __builtin_amdgcn_mfma_f32_32x32x16_bf16(bfr[t % 3], af, acc, 0, 0, 0);
    if(t < 29) loadB(&bfr[t % 3], t + 3);
  }

  __syncthreads();   // GEMM As reads done before stf2 aliases

  // ---------------- epilogue: +b2, LN2, lrelu, layer3 ----------------
  {
    const float* b2e = b2 + (size_t)e * 256;
    #pragma unroll
    for(int g = 0; g < 4; g++){
      int cb = wbase + g * 8 + kh * 4;
      f32x4 bb = *(const f32x4*)(b2e + cb);
      #pragma unroll
      for(int j = 0; j < 4; j++) acc[g * 4 + j] += bb[j];
    }
    // LN2 stats
    float al2, bt2;
    {
      float s = 0.f, q = 0.f;
      #pragma unroll
      for(int r = 0; r < 16; r++){ float x = acc[r]; s += x; q = fmaf(x, x, q); }
      s += __shfl_xor(s, 32); q += __shfl_xor(q, 32);
      if(kh == 0){
        float2 sq; sq.x = s; sq.y = q;
        *(float2*)(&stf[pr * 16 + w * 2]) = sq;
      }
      __syncthreads();
      float ssum = 0.f, qsum = 0.f;
      #pragma unroll
      for(int u = 0; u < 4; u++){
        f32x4 v = *(const f32x4*)&stf[pr * 16 + u * 4];
        ssum += v[0] + v[2]; qsum += v[1] + v[3];
      }
      float mu = ssum * (1.f / 256.f);
      float rs = rsqrtf(fmaf(-mu, mu, qsum * (1.f / 256.f)) + HEPS);
      al2 = rs; bt2 = -mu * rs;
    }
    // normalize + lrelu + layer3 (vectorized)
    const float* g2e  = g2  + (size_t)e * 256;
    const float* be2e = be2 + (size_t)e * 256;
    const float* W3e  = W3 + (size_t)e * 256 * 3;
    float o0 = 0.f, o1 = 0.f, o2 = 0.f;
    #pragma unroll
    for(int g = 0; g < 4; g++){
      int cb = wbase + g * 8 + kh * 4;
      f32x4 gg = *(const f32x4*)(g2e + cb);
      f32x4 ee = *(const f32x4*)(be2e + cb);
      float w3f[12];
      *(f32x4*)(w3f)     = *(const f32x4*)(W3e + cb * 3);
      *(f32x4*)(w3f + 4) = *(const f32x4*)(W3e + cb * 3 + 4);
      *(f32x4*)(w3f + 8) = *(const f32x4*)(W3e + cb * 3 + 8);
      #pragma unroll
      for(int j = 0; j < 4; j++){
        float x = fmaf(acc[g * 4 + j], al2, bt2);
        x = fmaf(x, gg[j], ee[j]);
        x = fmaxf(x, HSLOPE * x);
        o0 = fmaf(x, w3f[j * 3 + 0], o0);
        o1 = fmaf(x, w3f[j * 3 + 1], o1);
        o2 = fmaf(x, w3f[j * 3 + 2], o2);
      }
    }
    o0 += __shfl_xor(o0, 32); o1 += __shfl_xor(o1, 32); o2 += __shfl_xor(o2, 32);
    float* opart = stf + 512;   // [32][8][3] floats at [512..1280) — disjoint from stf[0..512)
    if(kh == 0){
      opart[pr * 24 + w * 3 + 0] = o0;
      opart[pr * 24 + w * 3 + 1] = o1;
      opart[pr * 24 + w * 3 + 2] = o2;
    }
    __syncthreads();
    if(tid < 96){
      int rr = tid / 3, c = tid - rr * 3;
      float v = b3[e * 3 + c];
      #pragma unroll
      for(int ww = 0; ww < 8; ww++) v += opart[rr * 24 + ww * 3 + c];
      out[(row0 + rr) * 3 + c] = v;
    }
  }
}

extern "C" void kernel_launch(void* const* d_in, const int* in_sizes, int n_in,
                              void* d_out, int out_size, void* d_ws, size_t ws_size,
                              hipStream_t stream) {
  const float* points = (const float*)d_in[0];
  const int*   cats   = (const int*)d_in[1];
  const float* W1  = (const float*)d_in[2];
  const float* b1  = (const float*)d_in[3];
  const float* g1  = (const float*)d_in[4];
  const float* be1 = (const float*)d_in[5];
  const float* W2  = (const float*)d_in[6];
  const float* b2  = (const float*)d_in[7];
  const float* g2  = (const float*)d_in[8];
  const float* be2 = (const float*)d_in[9];
  const float* W3  = (const float*)d_in[10];
  const float* b3  = (const float*)d_in[11];
  float* out = (float*)d_out;

  const size_t W2IMG = (size_t)NE * 512 * 256 * 2;   // 2.62 MB bf16 image
  const int grid = NB * NN / 32;                     // 8192 blocks

  if (ws_size >= W2IMG) {
    unsigned short* wsW2 = (unsigned short*)d_ws;
    prep_w2<<<dim3((NE * 512 * 256) / 256), dim3(256), 0, stream>>>(W2, wsW2);
    mlp_main<true><<<dim3(grid), dim3(512), 0, stream>>>(
        points, cats, W1, b1, g1, be1, W2, b2, g2, be2, W3, b3, wsW2, out);
  } else {
    mlp_main<false><<<dim3(grid), dim3(512), 0, stream>>>(
        points, cats, W1, b1, g1, be1, W2, b2, g2, be2, W3, b3, nullptr, out);
  }
}

// Round 12
// 153.513 us; speedup vs baseline: 1.0521x; 1.0521x over previous
//
#include <hip/hip_runtime.h>
#include <hip/hip_bf16.h>
#include <stdint.h>
#include <stddef.h>

#define NB 32
#define NN 8192
#define NH 512
#define NE 10
#define HEPS 1e-5f
#define HSLOPE 0.2f

typedef short short8 __attribute__((ext_vector_type(8)));
typedef float f32x4 __attribute__((ext_vector_type(4)));
typedef float f32x16 __attribute__((ext_vector_type(16)));

static __device__ __forceinline__ unsigned short sbf(float a){
  __hip_bfloat16 t = __float2bfloat16(a);
  return *reinterpret_cast<unsigned short*>(&t);
}
static __device__ __forceinline__ unsigned pkbf(float a, float b){
  float2 f2; f2.x = a; f2.y = b;
  __hip_bfloat162 t = __float22bfloat162_rn(f2);
  return *reinterpret_cast<unsigned*>(&t);
}

// ---------------------------------------------------------------------------
// Prep: W2 [E][512][256] f32 -> bf16 image for 32x32x16 fragments (as R10).
// [e][t(32)][col(256)][kh(2)][kk(8)]: a wave's 32-col frag at k-step t is
// one coalesced 16B/lane load.
// ---------------------------------------------------------------------------
__global__ __launch_bounds__(256) void prep_w2(const float* __restrict__ W2,
                                               unsigned short* __restrict__ ws){
  int idx = blockIdx.x * 256 + threadIdx.x;
  int col = idx & 255;
  int k   = (idx >> 8) & 511;
  int e   = idx >> 17;
  int t = k >> 4, kh = (k >> 3) & 1, kk = k & 7;
  ws[(((size_t)(e * 32 + t)) << 12) + (col << 4) + (kh << 3) + kk] = sbf(W2[idx]);
}

// ---------------------------------------------------------------------------
// Main (R12): R10 structure (256 thr, 4 waves, wave = 32 rows x 64 cols,
// 32KB LDS, 4 blocks/CU) with DEEP PREFETCH to cover L2/LDS latency:
//   B-frags 6-deep (12 x 16B loads in flight ~ 150-200 cyc cover vs L2 ~200),
//   A-frags 4-deep (ds_read latency ~64-120 cyc).
// R11 lesson: occupancy was not binding; GEMM was B-load-latency-bound at
// 3-deep. Everything else identical to R10.
// ---------------------------------------------------------------------------
template<bool PREP>
__global__ __launch_bounds__(256, 4) void mlp_main(
  const float* __restrict__ points, const int* __restrict__ cats,
  const float* __restrict__ W1, const float* __restrict__ b1,
  const float* __restrict__ g1, const float* __restrict__ be1,
  const float* __restrict__ W2f, const float* __restrict__ b2,
  const float* __restrict__ g2, const float* __restrict__ be2,
  const float* __restrict__ W3, const float* __restrict__ b3,
  const unsigned short* __restrict__ W2s,
  float* __restrict__ out)
{
  __shared__ unsigned short As[32 * 512];   // 32KB; frag t at [t*512]: [kh(2)][pr(32)][kk(8)]
  float* stf = (float*)As;                  // stats alias hw[0..512); opart hw[512..1280)

  const int tid  = (int)threadIdx.x;
  const int lane = tid & 63;
  const int w    = tid >> 6;            // wave 0..3
  const int pr   = lane & 31;           // point-row (C col)
  const int kh   = lane >> 5;           // k-half
  const size_t row0 = (size_t)blockIdx.x * 32;
  const int e = cats[row0 >> 13];
  const int wbase = w * 64;

  // ---------------- layer1 via 32x32x16 MFMA ----------------
  f32x16 a1[4];
  float al1, bt1;
  {
    const float* W1e = W1 + (size_t)e * 3 * NH;
    const float* b1e = b1 + (size_t)e * NH;
    short8 apf;                         // points as B-operand (n = point-row)
    {
      const float* pp = points + (row0 + pr) * 3;
      union { short8 s; unsigned u[4]; } v;
      v.s = short8{0,0,0,0,0,0,0,0};
      if(kh == 0){ v.u[0] = pkbf(pp[0], pp[1]); v.u[1] = pkbf(pp[2], 1.0f); }
      apf = v.s;
    }
    #pragma unroll
    for(int mi = 0; mi < 4; mi++){
      int col = w * 128 + mi * 32 + pr;      // A-operand m = lane&31
      union { short8 s; unsigned u[4]; } bw;
      bw.s = short8{0,0,0,0,0,0,0,0};
      if(kh == 0){
        bw.u[0] = pkbf(W1e[col], W1e[NH + col]);
        bw.u[1] = pkbf(W1e[2 * NH + col], b1e[col]);
      }
      f32x16 z = {0.f,0.f,0.f,0.f,0.f,0.f,0.f,0.f,0.f,0.f,0.f,0.f,0.f,0.f,0.f,0.f};
      a1[mi] = __builtin_amdgcn_mfma_f32_32x32x16_bf16(bw.s, apf, z, 0, 0, 0);
    }
    // LN1 stats: all of lane's values belong to point-row pr
    float s = 0.f, q = 0.f;
    #pragma unroll
    for(int mi = 0; mi < 4; mi++)
      #pragma unroll
      for(int r = 0; r < 16; r++){ float x = a1[mi][r]; s += x; q = fmaf(x, x, q); }
    s += __shfl_xor(s, 32); q += __shfl_xor(q, 32);
    if(kh == 0){
      float2 sq; sq.x = s; sq.y = q;
      *(float2*)(&stf[pr * 8 + w * 2]) = sq;
    }
    __syncthreads();
    {
      f32x4 v0 = *(const f32x4*)&stf[pr * 8];
      f32x4 v1 = *(const f32x4*)&stf[pr * 8 + 4];
      float ssum = v0[0] + v0[2] + v1[0] + v1[2];
      float qsum = v0[1] + v0[3] + v1[1] + v1[3];
      float mu = ssum * (1.f / NH);
      float rs = rsqrtf(fmaf(-mu, mu, qsum * (1.f / NH)) + HEPS);
      al1 = rs; bt1 = -mu * rs;
    }
    __syncthreads();   // stf fully read before As overwrite
  }
  // normalize + lrelu -> packed uint2 into frag-major As
  {
    const float* g1e  = g1  + (size_t)e * NH;
    const float* be1e = be1 + (size_t)e * NH;
    #pragma unroll
    for(int mi = 0; mi < 4; mi++){
      #pragma unroll
      for(int a = 0; a < 4; a++){
        int cb = w * 128 + mi * 32 + a * 8 + kh * 4;   // 4 feature cols
        f32x4 gg = *(const f32x4*)(g1e + cb);
        f32x4 ee = *(const f32x4*)(be1e + cb);
        float xr[4];
        #pragma unroll
        for(int j = 0; j < 4; j++){
          float x = fmaf(a1[mi][a * 4 + j], al1, bt1);
          x = fmaf(x, gg[j], ee[j]);
          xr[j] = fmaxf(x, HSLOPE * x);
        }
        uint2 pk; pk.x = pkbf(xr[0], xr[1]); pk.y = pkbf(xr[2], xr[3]);
        int addr = ((w * 8 + mi * 2 + (a >> 1)) << 9) + ((a & 1) << 8) + pr * 8 + kh * 4;
        *(uint2*)(&As[addr]) = pk;
      }
    }
  }

  // ---------------- B prefetch (W2 as A-operand), 6-deep ----------------
  auto loadB = [&](short8* dst, int t){
    #pragma unroll
    for(int mi = 0; mi < 2; mi++){
      if constexpr (PREP){
        const unsigned short* p = W2s + (((size_t)(e * 32 + t)) << 12)
                                + ((wbase + mi * 32 + pr) << 4) + (kh << 3);
        dst[mi] = *(const short8*)p;
      } else {
        const float* p = W2f + (((size_t)e * 512 + t * 16 + kh * 8) << 8)
                       + (wbase + mi * 32 + pr);
        short8 v;
        #pragma unroll
        for(int kk = 0; kk < 8; kk++) v[kk] = (short)sbf(p[(size_t)kk << 8]);
        dst[mi] = v;
      }
    }
  };
  short8 bfr[6][2];
  #pragma unroll
  for(int d = 0; d < 6; d++) loadB(bfr[d], d);   // fill during Phase-A tail

  __syncthreads();   // As complete

  // ---------------- GEMM: 32 barrier-free k-steps, deep-pipelined ----------------
  f32x16 acc[2];
  {
    f32x16 z = {0.f,0.f,0.f,0.f,0.f,0.f,0.f,0.f,0.f,0.f,0.f,0.f,0.f,0.f,0.f,0.f};
    acc[0] = z; acc[1] = z;
  }
  const int aoff = (kh << 8) + pr * 8;
  short8 af[4];
  #pragma unroll
  for(int d = 0; d < 4; d++) af[d] = *(const short8*)&As[(d << 9) + aoff];

  #pragma unroll
  for(int t = 0; t < 32; t++){
    short8 a = af[t & 3];
    if(t < 28) af[t & 3] = *(const short8*)&As[((t + 4) << 9) + aoff];
    acc[0] = __builtin_amdgcn_mfma_f32_32x32x16_bf16(bfr[t % 6][0], a, acc[0], 0, 0, 0);
    acc[1] = __builtin_amdgcn_mfma_f32_32x32x16_bf16(bfr[t % 6][1], a, acc[1], 0, 0, 0);
    if(t < 26) loadB(bfr[t % 6], t + 6);
  }

  __syncthreads();   // GEMM As reads done before stf2 aliases

  // ---------------- epilogue: +b2, LN2, lrelu, layer3 ----------------
  {
    const float* b2e = b2 + (size_t)e * 256;
    #pragma unroll
    for(int mi = 0; mi < 2; mi++)
      #pragma unroll
      for(int a = 0; a < 4; a++){
        int cb = wbase + mi * 32 + a * 8 + kh * 4;
        f32x4 bb = *(const f32x4*)(b2e + cb);
        #pragma unroll
        for(int j = 0; j < 4; j++) acc[mi][a * 4 + j] += bb[j];
      }
    // LN2 stats
    float al2, bt2;
    {
      float s = 0.f, q = 0.f;
      #pragma unroll
      for(int mi = 0; mi < 2; mi++)
        #pragma unroll
        for(int r = 0; r < 16; r++){ float x = acc[mi][r]; s += x; q = fmaf(x, x, q); }
      s += __shfl_xor(s, 32); q += __shfl_xor(q, 32);
      if(kh == 0){
        float2 sq; sq.x = s; sq.y = q;
        *(float2*)(&stf[pr * 8 + w * 2]) = sq;
      }
      __syncthreads();
      f32x4 v0 = *(const f32x4*)&stf[pr * 8];
      f32x4 v1 = *(const f32x4*)&stf[pr * 8 + 4];
      float ssum = v0[0] + v0[2] + v1[0] + v1[2];
      float qsum = v0[1] + v0[3] + v1[1] + v1[3];
      float mu = ssum * (1.f / 256.f);
      float rs = rsqrtf(fmaf(-mu, mu, qsum * (1.f / 256.f)) + HEPS);
      al2 = rs; bt2 = -mu * rs;
    }
    // normalize + lrelu + layer3 (vectorized)
    const float* g2e  = g2  + (size_t)e * 256;
    const float* be2e = be2 + (size_t)e * 256;
    const float* W3e  = W3 + (size_t)e * 256 * 3;
    float o0 = 0.f, o1 = 0.f, o2 = 0.f;
    #pragma unroll
    for(int mi = 0; mi < 2; mi++)
      #pragma unroll
      for(int a = 0; a < 4; a++){
        int cb = wbase + mi * 32 + a * 8 + kh * 4;
        f32x4 gg = *(const f32x4*)(g2e + cb);
        f32x4 ee = *(const f32x4*)(be2e + cb);
        float w3f[12];
        *(f32x4*)(w3f)     = *(const f32x4*)(W3e + cb * 3);
        *(f32x4*)(w3f + 4) = *(const f32x4*)(W3e + cb * 3 + 4);
        *(f32x4*)(w3f + 8) = *(const f32x4*)(W3e + cb * 3 + 8);
        #pragma unroll
        for(int j = 0; j < 4; j++){
          float x = fmaf(acc[mi][a * 4 + j], al2, bt2);
          x = fmaf(x, gg[j], ee[j]);
          x = fmaxf(x, HSLOPE * x);
          o0 = fmaf(x, w3f[j * 3 + 0], o0);
          o1 = fmaf(x, w3f[j * 3 + 1], o1);
          o2 = fmaf(x, w3f[j * 3 + 2], o2);
        }
      }
    o0 += __shfl_xor(o0, 32); o1 += __shfl_xor(o1, 32); o2 += __shfl_xor(o2, 32);
    float* opart = stf + 256;   // [32][4][3] at hw[512..1280)
    if(kh == 0){
      opart[pr * 12 + w * 3 + 0] = o0;
      opart[pr * 12 + w * 3 + 1] = o1;
      opart[pr * 12 + w * 3 + 2] = o2;
    }
    __syncthreads();
    if(tid < 96){
      int rr = tid / 3, c = tid - rr * 3;
      float v = b3[e * 3 + c];
      #pragma unroll
      for(int ww = 0; ww < 4; ww++) v += opart[rr * 12 + ww * 3 + c];
      out[(row0 + rr) * 3 + c] = v;
    }
  }
}

extern "C" void kernel_launch(void* const* d_in, const int* in_sizes, int n_in,
                              void* d_out, int out_size, void* d_ws, size_t ws_size,
                              hipStream_t stream) {
  const float* points = (const float*)d_in[0];
  const int*   cats   = (const int*)d_in[1];
  const float* W1  = (const float*)d_in[2];
  const float* b1  = (const float*)d_in[3];
  const float* g1  = (const float*)d_in[4];
  const float* be1 = (const float*)d_in[5];
  const float* W2  = (const float*)d_in[6];
  const float* b2  = (const float*)d_in[7];
  const float* g2  = (const float*)d_in[8];
  const float* be2 = (const float*)d_in[9];
  const float* W3  = (const float*)d_in[10];
  const float* b3  = (const float*)d_in[11];
  float* out = (float*)d_out;

  const size_t W2IMG = (size_t)NE * 512 * 256 * 2;   // 2.62 MB bf16 image
  const int grid = NB * NN / 32;                     // 8192 blocks

  if (ws_size >= W2IMG) {
    unsigned short* wsW2 = (unsigned short*)d_ws;
    prep_w2<<<dim3((NE * 512 * 256) / 256), dim3(256), 0, stream>>>(W2, wsW2);
    mlp_main<true><<<dim3(grid), dim3(256), 0, stream>>>(
        points, cats, W1, b1, g1, be1, W2, b2, g2, be2, W3, b3, wsW2, out);
  } else {
    mlp_main<false><<<dim3(grid), dim3(256), 0, stream>>>(
        points, cats, W1, b1, g1, be1, W2, b2, g2, be2, W3, b3, nullptr, out);
  }
}